// Round 1
// baseline (1710.383 us; speedup 1.0000x reference)
//
#include <hip/hip_runtime.h>
#include <math.h>

#define D_   4096
#define NIMG 16
#define NPER 64
#define RPER 512
#define NTOT (NIMG * NPER)   // 1024
#define RTOT (NIMG * RPER)   // 8192
#define DC   (D_ / 2)        // 2048
#define DT   (D_ / 4)        // 1024

// ---------------------------------------------------------------------------
// GEMM: C[m,n] = act( [resid[m,n] +] sum_k A[m,k]*B[n,k] + bias[n] )
// A: MxK row-major, B: NxK row-major (i.e. C = A @ B^T + bias)
// mode: 0 = none, 1 = relu, 2 = relu(resid + .)
// Block tile 64x64, 256 threads, each thread 4x4 outputs, K staged 16 at a time.
// Requires M%64==0, N%64==0, K%16==0 (true for all shapes here).
// ---------------------------------------------------------------------------
__global__ __launch_bounds__(256) void gemm_bt(
    const float* __restrict__ A, const float* __restrict__ B,
    const float* __restrict__ bias, const float* __restrict__ resid,
    float* __restrict__ C, int M, int N, int K, int mode)
{
    __shared__ __align__(16) float As[16][64];   // [k][m]
    __shared__ __align__(16) float Bs[16][64];   // [k][n]
    const int t  = threadIdx.x;
    const int tx = t & 15, ty = t >> 4;
    const int bm = blockIdx.y * 64, bn = blockIdx.x * 64;
    const int lrow = t >> 2;             // 0..63
    const int lk4  = (t & 3) << 2;       // 0,4,8,12

    float acc[4][4] = {};

    for (int k0 = 0; k0 < K; k0 += 16) {
        float4 a4 = *(const float4*)(A + (size_t)(bm + lrow) * K + k0 + lk4);
        float4 b4 = *(const float4*)(B + (size_t)(bn + lrow) * K + k0 + lk4);
        __syncthreads();   // previous iteration's reads complete
        As[lk4 + 0][lrow] = a4.x; As[lk4 + 1][lrow] = a4.y;
        As[lk4 + 2][lrow] = a4.z; As[lk4 + 3][lrow] = a4.w;
        Bs[lk4 + 0][lrow] = b4.x; Bs[lk4 + 1][lrow] = b4.y;
        Bs[lk4 + 2][lrow] = b4.z; Bs[lk4 + 3][lrow] = b4.w;
        __syncthreads();
#pragma unroll
        for (int kk = 0; kk < 16; ++kk) {
            float4 av = *(const float4*)&As[kk][ty << 2];
            float4 bv = *(const float4*)&Bs[kk][tx << 2];
            float a[4] = {av.x, av.y, av.z, av.w};
            float b[4] = {bv.x, bv.y, bv.z, bv.w};
#pragma unroll
            for (int i = 0; i < 4; ++i)
#pragma unroll
                for (int j = 0; j < 4; ++j)
                    acc[i][j] = fmaf(a[i], b[j], acc[i][j]);
        }
    }

    const int m0 = bm + (ty << 2), n0 = bn + (tx << 2);
#pragma unroll
    for (int i = 0; i < 4; ++i) {
        const int m = m0 + i;
#pragma unroll
        for (int j = 0; j < 4; ++j) {
            const int n = n0 + j;
            float v = acc[i][j] + bias[n];
            if (mode == 1) v = fmaxf(v, 0.f);
            else if (mode == 2) v = fmaxf(v + resid[(size_t)m * N + n], 0.f);
            C[(size_t)m * N + n] = v;
        }
    }
}

// ---------------------------------------------------------------------------
// atten[r] = sum_d ws[s[r],d] * wo[o[r],d] * phr[r,d] * Www[d]  + Wwb
// ---------------------------------------------------------------------------
__global__ __launch_bounds__(256) void atten_kernel(
    const float* __restrict__ ws, const float* __restrict__ wo,
    const float* __restrict__ phr, const int* __restrict__ rel,
    const float* __restrict__ Www, const float* __restrict__ Wwb,
    float* __restrict__ atten)
{
    const int r = blockIdx.x;
    const int s = rel[r * 3 + 1], o = rel[r * 3 + 2];
    const int t = threadIdx.x;
    const float4* pws = (const float4*)(ws + (size_t)s * D_);
    const float4* pwo = (const float4*)(wo + (size_t)o * D_);
    const float4* pph = (const float4*)(phr + (size_t)r * D_);
    const float4* pww = (const float4*)Www;
    float sum = 0.f;
    for (int q = t; q < D_ / 4; q += 256) {
        float4 a = pws[q], b = pwo[q], c = pph[q], w = pww[q];
        sum += a.x * b.x * c.x * w.x + a.y * b.y * c.y * w.y
             + a.z * b.z * c.z * w.z + a.w * b.w * c.w * w.w;
    }
    for (int off = 32; off > 0; off >>= 1) sum += __shfl_down(sum, off);
    __shared__ float red[4];
    if ((t & 63) == 0) red[t >> 6] = sum;
    __syncthreads();
    if (t == 0) atten[r] = red[0] + red[1] + red[2] + red[3] + Wwb[0];
}

// ---------------------------------------------------------------------------
// Per image: head = min(min s, min o); scatter-add atten into A[64][64];
// A = sigmoid(A) * (1-eye); S[j] = sum_k A[j][k]; Anorm[i][j] = A[i][j]/S[j]
// (note: denominator indexed by j — numpy broadcast of A/(A.sum(1)))
// ---------------------------------------------------------------------------
__global__ __launch_bounds__(256) void build_A(
    const int* __restrict__ rel, const float* __restrict__ atten,
    float* __restrict__ Anorm)
{
    const int g = blockIdx.x;
    const int t = threadIdx.x;
    __shared__ float Am[64][64];
    __shared__ float S[64];
    __shared__ int headSh;
    for (int i = t; i < 4096; i += 256) ((float*)Am)[i] = 0.f;
    if (t == 0) headSh = 0x7fffffff;

    int lmin = 0x7fffffff;
    for (int rr = t; rr < RPER; rr += 256) {
        const int base = (g * RPER + rr) * 3;
        const int s = rel[base + 1], o = rel[base + 2];
        lmin = min(lmin, min(s, o));
    }
    for (int off = 32; off > 0; off >>= 1) lmin = min(lmin, __shfl_down(lmin, off));
    __syncthreads();
    if ((t & 63) == 0) atomicMin(&headSh, lmin);
    __syncthreads();
    const int head = headSh;

    for (int rr = t; rr < RPER; rr += 256) {
        const int base = (g * RPER + rr) * 3;
        const int s = rel[base + 1] - head, o = rel[base + 2] - head;
        atomicAdd(&Am[s][o], atten[g * RPER + rr]);
    }
    __syncthreads();

    for (int idx = t; idx < 4096; idx += 256) {
        const int i = idx >> 6, j = idx & 63;
        float v = 1.f / (1.f + expf(-Am[i][j]));
        if (i == j) v = 0.f;
        Am[i][j] = v;
    }
    __syncthreads();

    if (t < 64) {
        float sum = 0.f;
        for (int k = 0; k < 64; ++k) sum += Am[t][k];
        S[t] = sum;
    }
    __syncthreads();

    float* outg = Anorm + (size_t)g * 4096;
    for (int idx = t; idx < 4096; idx += 256) {
        const int j = idx & 63;
        outg[idx] = ((const float*)Am)[idx] / S[j];
    }
}

// ---------------------------------------------------------------------------
// ctx[g*64+i, 0:2048]    = sum_j Anorm[g][i][j] * conv[g*64+j, :]
// ctx[g*64+i, 2048:4096] = sum_j Anorm[g][j][i] * conv[g*64+j, :]
// One block per (g,i); 256 threads cover 2048 cols as 2 float4 each.
// ---------------------------------------------------------------------------
__device__ __forceinline__ void fma4(float4& d, float s, const float4 c) {
    d.x = fmaf(s, c.x, d.x); d.y = fmaf(s, c.y, d.y);
    d.z = fmaf(s, c.z, d.z); d.w = fmaf(s, c.w, d.w);
}

__global__ __launch_bounds__(256) void ctx_kernel(
    const float* __restrict__ Anorm, const float* __restrict__ conv,
    float* __restrict__ ctx)
{
    const int g = blockIdx.x >> 6;
    const int i = blockIdx.x & 63;
    const int t = threadIdx.x;
    __shared__ float Arow[64], Acol[64];
    if (t < 64) Arow[t] = Anorm[(size_t)g * 4096 + i * 64 + t];
    else if (t < 128) { const int j = t - 64; Acol[j] = Anorm[(size_t)g * 4096 + j * 64 + i]; }
    __syncthreads();

    const float* cg = conv + (size_t)g * NPER * DC;
    float4 a0 = {0,0,0,0}, a1 = a0, a2 = a0, a3 = a0;
    for (int j = 0; j < 64; ++j) {
        const float ar = Arow[j], ac = Acol[j];
        float4 c0 = *(const float4*)(cg + (size_t)j * DC + (t << 2));
        float4 c1 = *(const float4*)(cg + (size_t)j * DC + 1024 + (t << 2));
        fma4(a0, ar, c0); fma4(a1, ar, c1);
        fma4(a2, ac, c0); fma4(a3, ac, c1);
    }
    float* crow = ctx + (size_t)(g * NPER + i) * D_;
    *(float4*)(crow + (t << 2))        = a0;
    *(float4*)(crow + 1024 + (t << 2)) = a1;
    *(float4*)(crow + 2048 + (t << 2)) = a2;
    *(float4*)(crow + 3072 + (t << 2)) = a3;
}

// ---------------------------------------------------------------------------
// In-place LayerNorm(1024) + affine + relu, one block per row, 256 thr x 4 el
// ---------------------------------------------------------------------------
__global__ __launch_bounds__(256) void ln_relu_kernel(
    float* __restrict__ h, const float* __restrict__ gamma,
    const float* __restrict__ beta)
{
    const int row = blockIdx.x;
    const int t = threadIdx.x;
    float* hr = h + (size_t)row * DT;
    float4 v = *(const float4*)(hr + (t << 2));
    float s  = v.x + v.y + v.z + v.w;
    float ss = v.x * v.x + v.y * v.y + v.z * v.z + v.w * v.w;
    for (int off = 32; off > 0; off >>= 1) {
        s  += __shfl_down(s, off);
        ss += __shfl_down(ss, off);
    }
    __shared__ float rs[4], rss[4];
    if ((t & 63) == 0) { rs[t >> 6] = s; rss[t >> 6] = ss; }
    __syncthreads();
    const float tot  = rs[0] + rs[1] + rs[2] + rs[3];
    const float tot2 = rss[0] + rss[1] + rss[2] + rss[3];
    const float mu   = tot * (1.f / DT);
    const float var  = tot2 * (1.f / DT) - mu * mu;
    const float rstd = rsqrtf(var + 1e-5f);
    float4 g4 = *(const float4*)(gamma + (t << 2));
    float4 b4 = *(const float4*)(beta + (t << 2));
    v.x = fmaxf(fmaf((v.x - mu) * rstd, g4.x, b4.x), 0.f);
    v.y = fmaxf(fmaf((v.y - mu) * rstd, g4.y, b4.y), 0.f);
    v.z = fmaxf(fmaf((v.z - mu) * rstd, g4.z, b4.z), 0.f);
    v.w = fmaxf(fmaf((v.w - mu) * rstd, g4.w, b4.w), 0.f);
    *(float4*)(hr + (t << 2)) = v;
}

// ---------------------------------------------------------------------------
extern "C" void kernel_launch(void* const* d_in, const int* in_sizes, int n_in,
                              void* d_out, int out_size, void* d_ws, size_t ws_size,
                              hipStream_t stream)
{
    const float* obj   = (const float*)d_in[0];
    const float* phr   = (const float*)d_in[1];
    const int*   rel   = (const int*)d_in[3];
    const float* Ws_w  = (const float*)d_in[5];
    const float* Ws_b  = (const float*)d_in[6];
    const float* Wo_w  = (const float*)d_in[7];
    const float* Wo_b  = (const float*)d_in[8];
    const float* Ww_w  = (const float*)d_in[9];
    const float* Ww_b  = (const float*)d_in[10];
    const float* Wc_w  = (const float*)d_in[11];
    const float* Wc_b  = (const float*)d_in[12];
    const float* Wt1_w = (const float*)d_in[13];
    const float* Wt1_b = (const float*)d_in[14];
    const float* ln_g  = (const float*)d_in[15];
    const float* ln_b  = (const float*)d_in[16];
    const float* Wt2_w = (const float*)d_in[17];
    const float* Wt2_b = (const float*)d_in[18];
    float* out = (float*)d_out;

    float* ws       = (float*)d_ws;
    float* ws_all   = ws;                       // 1024*4096
    float* wo_all   = ws + 4194304;             // 1024*4096
    float* conv_all = ws + 8388608;             // 1024*2048
    float* atten    = ws + 10485760;            // 8192
    float* Anorm    = ws + 10493952;            // 16*64*64
    float* ctx      = ws_all;                   // alias (ws_all dead after atten)
    float* h        = wo_all;                   // alias (wo_all dead after atten)

    const dim3 blk(256);
    gemm_bt<<<dim3(64, 16), blk, 0, stream>>>(obj, Ws_w, Ws_b, nullptr, ws_all,   NTOT, D_, D_, 0);
    gemm_bt<<<dim3(64, 16), blk, 0, stream>>>(obj, Wo_w, Wo_b, nullptr, wo_all,   NTOT, D_, D_, 0);
    gemm_bt<<<dim3(32, 16), blk, 0, stream>>>(obj, Wc_w, Wc_b, nullptr, conv_all, NTOT, DC, D_, 1);
    atten_kernel<<<dim3(RTOT), blk, 0, stream>>>(ws_all, wo_all, phr, rel, Ww_w, Ww_b, atten);
    build_A<<<dim3(NIMG), blk, 0, stream>>>(rel, atten, Anorm);
    ctx_kernel<<<dim3(1024), blk, 0, stream>>>(Anorm, conv_all, ctx);
    gemm_bt<<<dim3(16, 16), blk, 0, stream>>>(ctx, Wt1_w, Wt1_b, nullptr, h, NTOT, DT, D_, 0);
    ln_relu_kernel<<<dim3(NTOT), blk, 0, stream>>>(h, ln_g, ln_b);
    gemm_bt<<<dim3(64, 16), blk, 0, stream>>>(h, Wt2_w, Wt2_b, obj, out, NTOT, D_, DT, 2);
}

// Round 2
// 551.397 us; speedup vs baseline: 3.1019x; 3.1019x over previous
//
#include <hip/hip_runtime.h>
#include <hip/hip_bf16.h>
#include <math.h>

#define D_   4096
#define NIMG 16
#define NPER 64
#define RPER 512
#define NTOT (NIMG * NPER)   // 1024
#define RTOT (NIMG * RPER)   // 8192
#define DC   (D_ / 2)        // 2048
#define DT   (D_ / 4)        // 1024

typedef __attribute__((ext_vector_type(4))) float f32x4;
typedef __attribute__((ext_vector_type(8))) short bf16x8;

#define GLD16(gp, lp) __builtin_amdgcn_global_load_lds( \
    (const __attribute__((address_space(1))) unsigned int*)(gp), \
    (__attribute__((address_space(3))) unsigned int*)(lp), 16, 0, 0)

// ---------------------------------------------------------------------------
// f32 -> bf16 cast, 8 elems/thread
// ---------------------------------------------------------------------------
__global__ __launch_bounds__(256) void cast_bf16(
    const float* __restrict__ src, __hip_bfloat16* __restrict__ dst, int n)
{
    const int stride = gridDim.x * 256 * 8;
    for (int i = (blockIdx.x * 256 + threadIdx.x) * 8; i < n; i += stride) {
        float4 v0 = *(const float4*)(src + i);
        float4 v1 = *(const float4*)(src + i + 4);
        union { __hip_bfloat16 h[8]; ushort4 u[2]; } cv;
        cv.h[0] = __float2bfloat16(v0.x); cv.h[1] = __float2bfloat16(v0.y);
        cv.h[2] = __float2bfloat16(v0.z); cv.h[3] = __float2bfloat16(v0.w);
        cv.h[4] = __float2bfloat16(v1.x); cv.h[5] = __float2bfloat16(v1.y);
        cv.h[6] = __float2bfloat16(v1.z); cv.h[7] = __float2bfloat16(v1.w);
        *(ushort4*)(dst + i)     = cv.u[0];
        *(ushort4*)(dst + i + 4) = cv.u[1];
    }
}

// ---------------------------------------------------------------------------
// MFMA GEMM: C[m,n] = act([resid +] sum_k A[m,k]*B[n,k] + bias[n])
// A: MxK bf16 row-major, B: NxK bf16 row-major (C = A @ B^T).
// 128x128 tile, 256 thr (4 waves 2x2, each 64x64 = 4x4 16x16 frags), BK=32.
// global_load_lds(16B) with pre-swizzled source; ds_read_b128 XOR-swizzled.
// LDS row = 32 bf16 = 4 x 16B slots; slot s of row r holds K-quarter s^(r&3).
// Requires M%128==0, N%128==0, K%32==0.
// ---------------------------------------------------------------------------
__global__ __launch_bounds__(256) void gemm_mfma(
    const __hip_bfloat16* __restrict__ A, const __hip_bfloat16* __restrict__ B,
    const float* __restrict__ bias, const float* __restrict__ resid,
    float* __restrict__ C, int M, int N, int K, int mode)
{
    __shared__ __hip_bfloat16 As[128 * 32];
    __shared__ __hip_bfloat16 Bs[128 * 32];
    const int t    = threadIdx.x;
    const int lane = t & 63;
    const int wid  = t >> 6;
    const int wr = wid >> 1, wc = wid & 1;
    const int bm = blockIdx.y * 128, bn = blockIdx.x * 128;

    f32x4 acc[4][4] = {};

    // --- staging precompute: thread t serves linear 16B slots t and 256+t ---
    const int r0 = t >> 2;                       // row 0..63 (p=0); p=1 -> +64
    const int q  = (t & 3) ^ (r0 & 3);           // global K-quarter to fetch
    const int qoff = q * 8;                      // element offset in row
    const size_t arow0 = (size_t)(bm + r0) * K + qoff;
    const size_t arow1 = (size_t)(bm + r0 + 64) * K + qoff;
    const size_t brow0 = (size_t)(bn + r0) * K + qoff;
    const size_t brow1 = (size_t)(bn + r0 + 64) * K + qoff;
    __hip_bfloat16* AsW0 = As + wid * 512;           // wave-uniform LDS bases
    __hip_bfloat16* AsW1 = As + 2048 + wid * 512;
    __hip_bfloat16* BsW0 = Bs + wid * 512;
    __hip_bfloat16* BsW1 = Bs + 2048 + wid * 512;

    // --- fragment read precompute ---
    const int rfa  = wr * 64 + (lane & 15);          // + m*16
    const int rfb  = wc * 64 + (lane & 15);          // + n*16
    const int slot = (((lane >> 4) ^ (lane & 3)) << 3);  // swizzled elem offset

    for (int k0 = 0; k0 < K; k0 += 32) {
        __syncthreads();                      // WAR: prev compute done
        GLD16(A + arow0 + k0, AsW0);
        GLD16(A + arow1 + k0, AsW1);
        GLD16(B + brow0 + k0, BsW0);
        GLD16(B + brow1 + k0, BsW1);
        __syncthreads();                      // RAW: staging drained

        bf16x8 af[4], bfr[4];
#pragma unroll
        for (int m = 0; m < 4; ++m)
            af[m] = *(const bf16x8*)(As + (rfa + m * 16) * 32 + slot);
#pragma unroll
        for (int n = 0; n < 4; ++n)
            bfr[n] = *(const bf16x8*)(Bs + (rfb + n * 16) * 32 + slot);
#pragma unroll
        for (int m = 0; m < 4; ++m)
#pragma unroll
            for (int n = 0; n < 4; ++n)
                acc[m][n] = __builtin_amdgcn_mfma_f32_16x16x32_bf16(
                    af[m], bfr[n], acc[m][n], 0, 0, 0);
    }

    // --- epilogue: C/D layout col=lane&15, row=(lane>>4)*4+reg ---
    const int col0 = bn + wc * 64 + (lane & 15);
    const int row0 = bm + wr * 64 + ((lane >> 4) << 2);
#pragma unroll
    for (int m = 0; m < 4; ++m) {
#pragma unroll
        for (int n = 0; n < 4; ++n) {
            const int cn = col0 + n * 16;
            const float bz = bias[cn];
#pragma unroll
            for (int rg = 0; rg < 4; ++rg) {
                const int gm = row0 + m * 16 + rg;
                float v = acc[m][n][rg] + bz;
                if (mode == 1) v = fmaxf(v, 0.f);
                else if (mode == 2) v = fmaxf(v + resid[(size_t)gm * N + cn], 0.f);
                C[(size_t)gm * N + cn] = v;
            }
        }
    }
}

// ---------------------------------------------------------------------------
// atten[r] = sum_d ws[s[r],d] * wo[o[r],d] * phr[r,d] * Www[d]  + Wwb
// ---------------------------------------------------------------------------
__global__ __launch_bounds__(256) void atten_kernel(
    const float* __restrict__ ws, const float* __restrict__ wo,
    const float* __restrict__ phr, const int* __restrict__ rel,
    const float* __restrict__ Www, const float* __restrict__ Wwb,
    float* __restrict__ atten)
{
    const int r = blockIdx.x;
    const int s = rel[r * 3 + 1], o = rel[r * 3 + 2];
    const int t = threadIdx.x;
    const float4* pws = (const float4*)(ws + (size_t)s * D_);
    const float4* pwo = (const float4*)(wo + (size_t)o * D_);
    const float4* pph = (const float4*)(phr + (size_t)r * D_);
    const float4* pww = (const float4*)Www;
    float sum = 0.f;
    for (int qq = t; qq < D_ / 4; qq += 256) {
        float4 a = pws[qq], b = pwo[qq], c = pph[qq], w = pww[qq];
        sum += a.x * b.x * c.x * w.x + a.y * b.y * c.y * w.y
             + a.z * b.z * c.z * w.z + a.w * b.w * c.w * w.w;
    }
    for (int off = 32; off > 0; off >>= 1) sum += __shfl_down(sum, off);
    __shared__ float red[4];
    if ((t & 63) == 0) red[t >> 6] = sum;
    __syncthreads();
    if (t == 0) atten[r] = red[0] + red[1] + red[2] + red[3] + Wwb[0];
}

// ---------------------------------------------------------------------------
// Per image: head = min(min s, min o); scatter-add atten into A[64][64];
// A = sigmoid(A)*(1-eye); S[j] = sum_k A[j][k]; Anorm[i][j] = A[i][j]/S[j]
// ---------------------------------------------------------------------------
__global__ __launch_bounds__(256) void build_A(
    const int* __restrict__ rel, const float* __restrict__ atten,
    float* __restrict__ Anorm)
{
    const int g = blockIdx.x;
    const int t = threadIdx.x;
    __shared__ float Am[64][64];
    __shared__ float S[64];
    __shared__ int headSh;
    for (int i = t; i < 4096; i += 256) ((float*)Am)[i] = 0.f;
    if (t == 0) headSh = 0x7fffffff;

    int lmin = 0x7fffffff;
    for (int rr = t; rr < RPER; rr += 256) {
        const int base = (g * RPER + rr) * 3;
        lmin = min(lmin, min(rel[base + 1], rel[base + 2]));
    }
    for (int off = 32; off > 0; off >>= 1) lmin = min(lmin, __shfl_down(lmin, off));
    __syncthreads();
    if ((t & 63) == 0) atomicMin(&headSh, lmin);
    __syncthreads();
    const int head = headSh;

    for (int rr = t; rr < RPER; rr += 256) {
        const int base = (g * RPER + rr) * 3;
        atomicAdd(&Am[rel[base + 1] - head][rel[base + 2] - head],
                  atten[g * RPER + rr]);
    }
    __syncthreads();

    for (int idx = t; idx < 4096; idx += 256) {
        const int i = idx >> 6, j = idx & 63;
        float v = 1.f / (1.f + expf(-Am[i][j]));
        if (i == j) v = 0.f;
        Am[i][j] = v;
    }
    __syncthreads();

    if (t < 64) {
        float sum = 0.f;
        for (int k = 0; k < 64; ++k) sum += Am[t][k];
        S[t] = sum;
    }
    __syncthreads();

    float* outg = Anorm + (size_t)g * 4096;
    for (int idx = t; idx < 4096; idx += 256) {
        const int j = idx & 63;
        outg[idx] = ((const float*)Am)[idx] / S[j];
    }
}

// ---------------------------------------------------------------------------
// ctx[g*64+i, 0:2048]    = sum_j Anorm[g][i][j] * conv[g*64+j, :]
// ctx[g*64+i, 2048:4096] = sum_j Anorm[g][j][i] * conv[g*64+j, :]
// output bf16 (feeds Wt1 MFMA gemm)
// ---------------------------------------------------------------------------
__device__ __forceinline__ void fma4(float4& d, float s, const float4 c) {
    d.x = fmaf(s, c.x, d.x); d.y = fmaf(s, c.y, d.y);
    d.z = fmaf(s, c.z, d.z); d.w = fmaf(s, c.w, d.w);
}
__device__ __forceinline__ void st4bf(__hip_bfloat16* p, float4 v) {
    union { __hip_bfloat16 h[4]; ushort4 u; } cv;
    cv.h[0] = __float2bfloat16(v.x); cv.h[1] = __float2bfloat16(v.y);
    cv.h[2] = __float2bfloat16(v.z); cv.h[3] = __float2bfloat16(v.w);
    *(ushort4*)p = cv.u;
}

__global__ __launch_bounds__(256) void ctx_kernel(
    const float* __restrict__ Anorm, const float* __restrict__ conv,
    __hip_bfloat16* __restrict__ ctx)
{
    const int g = blockIdx.x >> 6;
    const int i = blockIdx.x & 63;
    const int t = threadIdx.x;
    __shared__ float Arow[64], Acol[64];
    if (t < 64) Arow[t] = Anorm[(size_t)g * 4096 + i * 64 + t];
    else if (t < 128) { const int j = t - 64; Acol[j] = Anorm[(size_t)g * 4096 + j * 64 + i]; }
    __syncthreads();

    const float* cg = conv + (size_t)g * NPER * DC;
    float4 a0 = {0,0,0,0}, a1 = a0, a2 = a0, a3 = a0;
    for (int j = 0; j < 64; ++j) {
        const float ar = Arow[j], ac = Acol[j];
        float4 c0 = *(const float4*)(cg + (size_t)j * DC + (t << 2));
        float4 c1 = *(const float4*)(cg + (size_t)j * DC + 1024 + (t << 2));
        fma4(a0, ar, c0); fma4(a1, ar, c1);
        fma4(a2, ac, c0); fma4(a3, ac, c1);
    }
    __hip_bfloat16* crow = ctx + (size_t)(g * NPER + i) * D_;
    st4bf(crow + (t << 2),        a0);
    st4bf(crow + 1024 + (t << 2), a1);
    st4bf(crow + 2048 + (t << 2), a2);
    st4bf(crow + 3072 + (t << 2), a3);
}

// ---------------------------------------------------------------------------
// LayerNorm(1024) + affine + relu; f32 in, bf16 out. One block per row.
// ---------------------------------------------------------------------------
__global__ __launch_bounds__(256) void ln_relu_kernel(
    const float* __restrict__ h, const float* __restrict__ gamma,
    const float* __restrict__ beta, __hip_bfloat16* __restrict__ hb)
{
    const int row = blockIdx.x;
    const int t = threadIdx.x;
    const float* hr = h + (size_t)row * DT;
    float4 v = *(const float4*)(hr + (t << 2));
    float s  = v.x + v.y + v.z + v.w;
    float ss = v.x * v.x + v.y * v.y + v.z * v.z + v.w * v.w;
    for (int off = 32; off > 0; off >>= 1) {
        s  += __shfl_down(s, off);
        ss += __shfl_down(ss, off);
    }
    __shared__ float rs[4], rss[4];
    if ((t & 63) == 0) { rs[t >> 6] = s; rss[t >> 6] = ss; }
    __syncthreads();
    const float tot  = rs[0] + rs[1] + rs[2] + rs[3];
    const float tot2 = rss[0] + rss[1] + rss[2] + rss[3];
    const float mu   = tot * (1.f / DT);
    const float var  = tot2 * (1.f / DT) - mu * mu;
    const float rstd = rsqrtf(var + 1e-5f);
    float4 g4 = *(const float4*)(gamma + (t << 2));
    float4 b4 = *(const float4*)(beta + (t << 2));
    float4 o;
    o.x = fmaxf(fmaf((v.x - mu) * rstd, g4.x, b4.x), 0.f);
    o.y = fmaxf(fmaf((v.y - mu) * rstd, g4.y, b4.y), 0.f);
    o.z = fmaxf(fmaf((v.z - mu) * rstd, g4.z, b4.z), 0.f);
    o.w = fmaxf(fmaf((v.w - mu) * rstd, g4.w, b4.w), 0.f);
    st4bf(hb + (size_t)row * DT + (t << 2), o);
}

// ---------------------------------------------------------------------------
extern "C" void kernel_launch(void* const* d_in, const int* in_sizes, int n_in,
                              void* d_out, int out_size, void* d_ws, size_t ws_size,
                              hipStream_t stream)
{
    const float* obj   = (const float*)d_in[0];
    const float* phr   = (const float*)d_in[1];
    const int*   rel   = (const int*)d_in[3];
    const float* Ws_w  = (const float*)d_in[5];
    const float* Ws_b  = (const float*)d_in[6];
    const float* Wo_w  = (const float*)d_in[7];
    const float* Wo_b  = (const float*)d_in[8];
    const float* Ww_w  = (const float*)d_in[9];
    const float* Ww_b  = (const float*)d_in[10];
    const float* Wc_w  = (const float*)d_in[11];
    const float* Wc_b  = (const float*)d_in[12];
    const float* Wt1_w = (const float*)d_in[13];
    const float* Wt1_b = (const float*)d_in[14];
    const float* ln_g  = (const float*)d_in[15];
    const float* ln_b  = (const float*)d_in[16];
    const float* Wt2_w = (const float*)d_in[17];
    const float* Wt2_b = (const float*)d_in[18];
    float* out = (float*)d_out;

    float* ws = (float*)d_ws;
    // layout (float slots); aliases noted. peak ~92.6 MB
    __hip_bfloat16* wbuf   = (__hip_bfloat16*)(ws);            // 16.8M bf16 = [0, 8388608)
    __hip_bfloat16* obj_bf = (__hip_bfloat16*)(ws + 8388608);  // 4.2M bf16 (dies after conv)
    __hip_bfloat16* ctx_bf = (__hip_bfloat16*)(ws + 8388608);  // 8.4M bf16 (alias obj_bf)
    float* ws_all   = ws + 12582912;   // 4.2M f32 (dies after atten)
    float* h_f32    = ws + 12582912;   // 1.05M f32 (alias ws_all)
    float* wo_all   = ws + 16777216;   // 4.2M f32 (dies after atten)
    __hip_bfloat16* h_bf = (__hip_bfloat16*)(ws + 16777216);   // alias wo_all
    float* conv_all = ws + 20971520;   // 2.1M f32
    float* atten    = ws + 23068672;   // 8192
    float* Anorm    = ws + 23076864;   // 65536

    const dim3 blk(256);
    // casts (stream-ordered; wbuf reused per-GEMM)
    cast_bf16<<<dim3(2048), blk, 0, stream>>>(obj, obj_bf, NTOT * D_);
    cast_bf16<<<dim3(4096), blk, 0, stream>>>(Ws_w, wbuf, D_ * D_);
    gemm_mfma<<<dim3(32, 8), blk, 0, stream>>>(obj_bf, wbuf, Ws_b, nullptr, ws_all, NTOT, D_, D_, 0);
    cast_bf16<<<dim3(4096), blk, 0, stream>>>(Wo_w, wbuf, D_ * D_);
    gemm_mfma<<<dim3(32, 8), blk, 0, stream>>>(obj_bf, wbuf, Wo_b, nullptr, wo_all, NTOT, D_, D_, 0);
    cast_bf16<<<dim3(4096), blk, 0, stream>>>(Wc_w, wbuf, DC * D_);
    gemm_mfma<<<dim3(16, 8), blk, 0, stream>>>(obj_bf, wbuf, Wc_b, nullptr, conv_all, NTOT, DC, D_, 1);

    atten_kernel<<<dim3(RTOT), blk, 0, stream>>>(ws_all, wo_all, phr, rel, Ww_w, Ww_b, atten);
    build_A<<<dim3(NIMG), blk, 0, stream>>>(rel, atten, Anorm);
    ctx_kernel<<<dim3(1024), blk, 0, stream>>>(Anorm, conv_all, ctx_bf);

    cast_bf16<<<dim3(2048), blk, 0, stream>>>(Wt1_w, wbuf, DT * D_);
    gemm_mfma<<<dim3(8, 8), blk, 0, stream>>>(ctx_bf, wbuf, Wt1_b, nullptr, h_f32, NTOT, DT, D_, 0);
    ln_relu_kernel<<<dim3(NTOT), blk, 0, stream>>>(h_f32, ln_g, ln_b, h_bf);
    cast_bf16<<<dim3(2048), blk, 0, stream>>>(Wt2_w, wbuf, D_ * DT);
    gemm_mfma<<<dim3(32, 8), blk, 0, stream>>>(h_bf, wbuf, Wt2_b, obj, out, NTOT, D_, DT, 2);
}

// Round 3
// 339.899 us; speedup vs baseline: 5.0320x; 1.6222x over previous
//
#include <hip/hip_runtime.h>
#include <hip/hip_bf16.h>
#include <math.h>

#define D_   4096
#define NIMG 16
#define NPER 64
#define RPER 512
#define NTOT 1024
#define RTOT 8192
#define DC   2048
#define DT   1024
#define LDO  10240   // fused output row stride (4096 ws | 4096 wo | 2048 conv)

typedef __attribute__((ext_vector_type(4))) float f32x4;
typedef __attribute__((ext_vector_type(8))) short bf16x8;

#define GLD16(gp, lp) __builtin_amdgcn_global_load_lds( \
    (const __attribute__((address_space(1))) unsigned int*)(gp), \
    (__attribute__((address_space(3))) unsigned int*)(lp), 16, 0, 0)

// ---------------------------------------------------------------------------
// multi-region f32 -> bf16 cast. Each block converts 2048 elems (all region
// sizes are multiples of 2048). Region picked by cumulative block starts.
// ---------------------------------------------------------------------------
struct Cast4 {
    const float* src0; const float* src1; const float* src2; const float* src3;
    __hip_bfloat16* dst0; __hip_bfloat16* dst1; __hip_bfloat16* dst2; __hip_bfloat16* dst3;
    int s1, s2, s3;
};

__global__ __launch_bounds__(256) void cast_multi(Cast4 a)
{
    const int b = blockIdx.x;
    const float* s; __hip_bfloat16* d; int rb;
    if (b < a.s1)      { s = a.src0; d = a.dst0; rb = b; }
    else if (b < a.s2) { s = a.src1; d = a.dst1; rb = b - a.s1; }
    else if (b < a.s3) { s = a.src2; d = a.dst2; rb = b - a.s2; }
    else               { s = a.src3; d = a.dst3; rb = b - a.s3; }
    const int i = (rb * 256 + threadIdx.x) * 8;
    float4 v0 = *(const float4*)(s + i);
    float4 v1 = *(const float4*)(s + i + 4);
    union { __hip_bfloat16 h[8]; ushort4 u[2]; } cv;
    cv.h[0] = __float2bfloat16(v0.x); cv.h[1] = __float2bfloat16(v0.y);
    cv.h[2] = __float2bfloat16(v0.z); cv.h[3] = __float2bfloat16(v0.w);
    cv.h[4] = __float2bfloat16(v1.x); cv.h[5] = __float2bfloat16(v1.y);
    cv.h[6] = __float2bfloat16(v1.z); cv.h[7] = __float2bfloat16(v1.w);
    *(ushort4*)(d + i)     = cv.u[0];
    *(ushort4*)(d + i + 4) = cv.u[1];
}

// ---------------------------------------------------------------------------
// concat biases: cbias[0:4096)=Ws_b, [4096:8192)=Wo_b, [8192:10240)=Wc_b
// ---------------------------------------------------------------------------
__global__ __launch_bounds__(256) void concat_bias(
    const float* __restrict__ b0, const float* __restrict__ b1,
    const float* __restrict__ b2, float* __restrict__ cb)
{
    const int i = blockIdx.x * 256 + threadIdx.x;
    float v;
    if (i < 4096) v = b0[i];
    else if (i < 8192) v = b1[i - 4096];
    else v = b2[i - 8192];
    cb[i] = v;
}

// ---------------------------------------------------------------------------
// MFMA GEMM, C = A @ B^T (+bias, act). bf16 in, f32 out.
// BM=64 x BN tile, 256 thr (2x2 waves, wave tile 32 x BN/2), BK=32.
// Triple-buffered LDS, stage-1-ahead with counted vmcnt + raw s_barrier
// (1 barrier/iter; WAR safe: buf[t%3] overwritten only at iter t+2, which any
// wave reaches only after barrier(t+1), by which all lgkmcnt-gated reads of
// iter t completed).
// LDS row = 32 bf16 = 4 x 16B slots; slot s of row r holds K-quarter s^(r&3)
// (XOR swizzle via pre-swizzled global source; gld_lds dest stays linear).
// mode: 0 = +bias; 2 = relu(resid + . + bias); 3 = +bias, relu iff col>=reluStart
// ---------------------------------------------------------------------------
template<int BN>
__global__ __launch_bounds__(256) void gemm_dp(
    const ushort* __restrict__ A, const ushort* __restrict__ B,
    const float* __restrict__ bias, const float* __restrict__ resid,
    float* __restrict__ C, int M, int K, int ldc, int mode, int reluStart)
{
    constexpr int MREP = 2;
    constexpr int NREP = BN / 32;
    constexpr int SLOTS_A = 256;                 // 64 rows * 4 slots
    constexpr int SLOTS_B = BN * 4;
    constexpr int NCH = (SLOTS_A + SLOTS_B) / 64;
    constexpr int NPW = NCH / 4;                 // gld_lds per thread per stage
    constexpr int BUFE = (SLOTS_A + SLOTS_B) * 8;

    __shared__ ushort lds[3][BUFE];

    const int t = threadIdx.x;
    const int lane = t & 63;
    const int wid = t >> 6;
    const int wr = wid >> 1, wc = wid & 1;

    const int MT = M >> 6;
    const int G = gridDim.x;
    const int bid = blockIdx.x;
    const int wgid = (bid & 7) * (G >> 3) + (bid >> 3);   // XCD swizzle (G%8==0)
    const int nt = wgid / MT, mt = wgid % MT;             // nt-groups stay on one XCD
    const int bm = mt * 64, bn = nt * BN;

    // --- staging precompute: wave w serves 64-slot chunks {w, w+4, w+8} ---
    const ushort* gp[NPW];
    int loff[NPW];
#pragma unroll
    for (int i = 0; i < NPW; ++i) {
        const int ch = wid + i * 4;
        const bool isA = ch < 4;
        const int slot = (isA ? ch : ch - 4) * 64 + lane;
        const int row = slot >> 2;
        const int q = (slot & 3) ^ (row & 3);             // pre-swizzled source
        gp[i] = (isA ? A + (size_t)(bm + row) * K : B + (size_t)(bn + row) * K) + q * 8;
        loff[i] = (isA ? 0 : SLOTS_A * 8) + slot * 8;     // linear LDS dest
    }

    // --- fragment read offsets (swizzled) ---
    int aoff[MREP], boff[NREP];
    const int sx = (((lane >> 4) ^ (lane & 3))) * 8;
#pragma unroll
    for (int m = 0; m < MREP; ++m)
        aoff[m] = (wr * 32 + (lane & 15) + m * 16) * 32 + sx;
#pragma unroll
    for (int n = 0; n < NREP; ++n)
        boff[n] = SLOTS_A * 8 + (wc * (BN / 2) + (lane & 15) + n * 16) * 32 + sx;

    f32x4 acc[MREP][NREP] = {};

    const int NT = K >> 5;
    // prologue: stage tile 0 -> buf 0
#pragma unroll
    for (int i = 0; i < NPW; ++i) GLD16(gp[i], &lds[0][loff[i]]);

    for (int tt = 0; tt < NT; ++tt) {
        if (tt + 1 < NT) {
            const int nb = (tt + 1) % 3;
            const int kpos = (tt + 1) << 5;
#pragma unroll
            for (int i = 0; i < NPW; ++i) GLD16(gp[i] + kpos, &lds[nb][loff[i]]);
            if constexpr (NPW == 3) asm volatile("s_waitcnt vmcnt(3)" ::: "memory");
            else                    asm volatile("s_waitcnt vmcnt(2)" ::: "memory");
        } else {
            asm volatile("s_waitcnt vmcnt(0)" ::: "memory");
        }
        __builtin_amdgcn_sched_barrier(0);
        __builtin_amdgcn_s_barrier();
        __builtin_amdgcn_sched_barrier(0);

        const ushort* lb = lds[tt % 3];
        bf16x8 af[MREP], bfv[NREP];
#pragma unroll
        for (int m = 0; m < MREP; ++m) af[m] = *(const bf16x8*)(lb + aoff[m]);
#pragma unroll
        for (int n = 0; n < NREP; ++n) bfv[n] = *(const bf16x8*)(lb + boff[n]);
#pragma unroll
        for (int m = 0; m < MREP; ++m)
#pragma unroll
            for (int n = 0; n < NREP; ++n)
                acc[m][n] = __builtin_amdgcn_mfma_f32_16x16x32_bf16(
                    af[m], bfv[n], acc[m][n], 0, 0, 0);
    }

    // --- epilogue: C/D map col=lane&15, row=(lane>>4)*4+reg ---
    const int col0 = bn + wc * (BN / 2) + (lane & 15);
    const int row0 = bm + wr * 32 + ((lane >> 4) << 2);
#pragma unroll
    for (int m = 0; m < MREP; ++m) {
#pragma unroll
        for (int n = 0; n < NREP; ++n) {
            const int cn = col0 + n * 16;
            const float bz = bias[cn];
#pragma unroll
            for (int rg = 0; rg < 4; ++rg) {
                const int gm = row0 + m * 16 + rg;
                float v = acc[m][n][rg] + bz;
                if (mode == 2) v = fmaxf(v + resid[(size_t)gm * ldc + cn], 0.f);
                else if (mode == 3 && cn >= reluStart) v = fmaxf(v, 0.f);
                C[(size_t)gm * ldc + cn] = v;
            }
        }
    }
}

// ---------------------------------------------------------------------------
// atten[r] = sum_d ws[s[r],d] * wo[o[r],d] * phr[r,d] * Www[d]  + Wwb
// ws/wo live inside fused output (row stride LDO, col offsets 0 / 4096)
// ---------------------------------------------------------------------------
__global__ __launch_bounds__(256) void atten_kernel(
    const float* __restrict__ allout, const float* __restrict__ phr,
    const int* __restrict__ rel, const float* __restrict__ Www,
    const float* __restrict__ Wwb, float* __restrict__ atten)
{
    const int r = blockIdx.x;
    const int s = rel[r * 3 + 1], o = rel[r * 3 + 2];
    const int t = threadIdx.x;
    const float4* pws = (const float4*)(allout + (size_t)s * LDO);
    const float4* pwo = (const float4*)(allout + (size_t)o * LDO + 4096);
    const float4* pph = (const float4*)(phr + (size_t)r * D_);
    const float4* pww = (const float4*)Www;
    float sum = 0.f;
    for (int qq = t; qq < D_ / 4; qq += 256) {
        float4 a = pws[qq], b = pwo[qq], c = pph[qq], w = pww[qq];
        sum += a.x * b.x * c.x * w.x + a.y * b.y * c.y * w.y
             + a.z * b.z * c.z * w.z + a.w * b.w * c.w * w.w;
    }
    for (int off = 32; off > 0; off >>= 1) sum += __shfl_down(sum, off);
    __shared__ float red[4];
    if ((t & 63) == 0) red[t >> 6] = sum;
    __syncthreads();
    if (t == 0) atten[r] = red[0] + red[1] + red[2] + red[3] + Wwb[0];
}

// ---------------------------------------------------------------------------
// Per image: head = min(min s, min o); scatter-add atten into A[64][64];
// A = sigmoid(A)*(1-eye); S[j] = sum_k A[j][k]; Anorm[i][j] = A[i][j]/S[j]
// ---------------------------------------------------------------------------
__global__ __launch_bounds__(256) void build_A(
    const int* __restrict__ rel, const float* __restrict__ atten,
    float* __restrict__ Anorm)
{
    const int g = blockIdx.x;
    const int t = threadIdx.x;
    __shared__ float Am[64][64];
    __shared__ float S[64];
    __shared__ int headSh;
    for (int i = t; i < 4096; i += 256) ((float*)Am)[i] = 0.f;
    if (t == 0) headSh = 0x7fffffff;

    int lmin = 0x7fffffff;
    for (int rr = t; rr < RPER; rr += 256) {
        const int base = (g * RPER + rr) * 3;
        lmin = min(lmin, min(rel[base + 1], rel[base + 2]));
    }
    for (int off = 32; off > 0; off >>= 1) lmin = min(lmin, __shfl_down(lmin, off));
    __syncthreads();
    if ((t & 63) == 0) atomicMin(&headSh, lmin);
    __syncthreads();
    const int head = headSh;

    for (int rr = t; rr < RPER; rr += 256) {
        const int base = (g * RPER + rr) * 3;
        atomicAdd(&Am[rel[base + 1] - head][rel[base + 2] - head],
                  atten[g * RPER + rr]);
    }
    __syncthreads();

    for (int idx = t; idx < 4096; idx += 256) {
        const int i = idx >> 6, j = idx & 63;
        float v = 1.f / (1.f + expf(-Am[i][j]));
        if (i == j) v = 0.f;
        Am[i][j] = v;
    }
    __syncthreads();

    if (t < 64) {
        float sum = 0.f;
        for (int k = 0; k < 64; ++k) sum += Am[t][k];
        S[t] = sum;
    }
    __syncthreads();

    float* outg = Anorm + (size_t)g * 4096;
    for (int idx = t; idx < 4096; idx += 256) {
        const int j = idx & 63;
        outg[idx] = ((const float*)Am)[idx] / S[j];
    }
}

// ---------------------------------------------------------------------------
// ctx[g*64+i, 0:2048]    = sum_j Anorm[g][i][j] * conv[g*64+j, :]
// ctx[g*64+i, 2048:4096] = sum_j Anorm[g][j][i] * conv[g*64+j, :]
// conv lives in fused output at col 8192, row stride LDO. Output bf16.
// ---------------------------------------------------------------------------
__device__ __forceinline__ void fma4(float4& d, float s, const float4 c) {
    d.x = fmaf(s, c.x, d.x); d.y = fmaf(s, c.y, d.y);
    d.z = fmaf(s, c.z, d.z); d.w = fmaf(s, c.w, d.w);
}
__device__ __forceinline__ void st4bf(__hip_bfloat16* p, float4 v) {
    union { __hip_bfloat16 h[4]; ushort4 u; } cv;
    cv.h[0] = __float2bfloat16(v.x); cv.h[1] = __float2bfloat16(v.y);
    cv.h[2] = __float2bfloat16(v.z); cv.h[3] = __float2bfloat16(v.w);
    *(ushort4*)p = cv.u;
}

__global__ __launch_bounds__(256) void ctx_kernel(
    const float* __restrict__ Anorm, const float* __restrict__ allout,
    __hip_bfloat16* __restrict__ ctx)
{
    const int g = blockIdx.x >> 6;
    const int i = blockIdx.x & 63;
    const int t = threadIdx.x;
    __shared__ float Arow[64], Acol[64];
    if (t < 64) Arow[t] = Anorm[(size_t)g * 4096 + i * 64 + t];
    else if (t < 128) { const int j = t - 64; Acol[j] = Anorm[(size_t)g * 4096 + j * 64 + i]; }
    __syncthreads();

    const float* cg = allout + (size_t)g * NPER * LDO + 8192;
    float4 a0 = {0,0,0,0}, a1 = a0, a2 = a0, a3 = a0;
    for (int j = 0; j < 64; ++j) {
        const float ar = Arow[j], ac = Acol[j];
        float4 c0 = *(const float4*)(cg + (size_t)j * LDO + (t << 2));
        float4 c1 = *(const float4*)(cg + (size_t)j * LDO + 1024 + (t << 2));
        fma4(a0, ar, c0); fma4(a1, ar, c1);
        fma4(a2, ac, c0); fma4(a3, ac, c1);
    }
    __hip_bfloat16* crow = ctx + (size_t)(g * NPER + i) * D_;
    st4bf(crow + (t << 2),        a0);
    st4bf(crow + 1024 + (t << 2), a1);
    st4bf(crow + 2048 + (t << 2), a2);
    st4bf(crow + 3072 + (t << 2), a3);
}

// ---------------------------------------------------------------------------
// LayerNorm(1024) + affine + relu; f32 in, bf16 out. One block per row.
// ---------------------------------------------------------------------------
__global__ __launch_bounds__(256) void ln_relu_kernel(
    const float* __restrict__ h, const float* __restrict__ gamma,
    const float* __restrict__ beta, __hip_bfloat16* __restrict__ hb)
{
    const int row = blockIdx.x;
    const int t = threadIdx.x;
    const float* hr = h + (size_t)row * DT;
    float4 v = *(const float4*)(hr + (t << 2));
    float s  = v.x + v.y + v.z + v.w;
    float ss = v.x * v.x + v.y * v.y + v.z * v.z + v.w * v.w;
    for (int off = 32; off > 0; off >>= 1) {
        s  += __shfl_down(s, off);
        ss += __shfl_down(ss, off);
    }
    __shared__ float rs[4], rss[4];
    if ((t & 63) == 0) { rs[t >> 6] = s; rss[t >> 6] = ss; }
    __syncthreads();
    const float tot  = rs[0] + rs[1] + rs[2] + rs[3];
    const float tot2 = rss[0] + rss[1] + rss[2] + rss[3];
    const float mu   = tot * (1.f / DT);
    const float var  = tot2 * (1.f / DT) - mu * mu;
    const float rstd = rsqrtf(var + 1e-5f);
    float4 g4 = *(const float4*)(gamma + (t << 2));
    float4 b4 = *(const float4*)(beta + (t << 2));
    float4 o;
    o.x = fmaxf(fmaf((v.x - mu) * rstd, g4.x, b4.x), 0.f);
    o.y = fmaxf(fmaf((v.y - mu) * rstd, g4.y, b4.y), 0.f);
    o.z = fmaxf(fmaf((v.z - mu) * rstd, g4.z, b4.z), 0.f);
    o.w = fmaxf(fmaf((v.w - mu) * rstd, g4.w, b4.w), 0.f);
    st4bf(hb + (size_t)row * DT + (t << 2), o);
}

// ---------------------------------------------------------------------------
extern "C" void kernel_launch(void* const* d_in, const int* in_sizes, int n_in,
                              void* d_out, int out_size, void* d_ws, size_t ws_size,
                              hipStream_t stream)
{
    const float* obj   = (const float*)d_in[0];
    const float* phr   = (const float*)d_in[1];
    const int*   rel   = (const int*)d_in[3];
    const float* Ws_w  = (const float*)d_in[5];
    const float* Ws_b  = (const float*)d_in[6];
    const float* Wo_w  = (const float*)d_in[7];
    const float* Wo_b  = (const float*)d_in[8];
    const float* Ww_w  = (const float*)d_in[9];
    const float* Ww_b  = (const float*)d_in[10];
    const float* Wc_w  = (const float*)d_in[11];
    const float* Wc_b  = (const float*)d_in[12];
    const float* Wt1_w = (const float*)d_in[13];
    const float* Wt1_b = (const float*)d_in[14];
    const float* ln_g  = (const float*)d_in[15];
    const float* ln_b  = (const float*)d_in[16];
    const float* Wt2_w = (const float*)d_in[17];
    const float* Wt2_b = (const float*)d_in[18];
    float* out = (float*)d_out;

    float* ws = (float*)d_ws;
    // workspace layout (float units), peak ~134.6 MB:
    __hip_bfloat16* wbuf   = (__hip_bfloat16*)ws;              // Ws|Wo|Wc concat, 41.9M bf16
    __hip_bfloat16* wbuf_t1 = wbuf;                            // reuse after fused GEMM
    __hip_bfloat16* wbuf_t2 = wbuf + 4194304;
    __hip_bfloat16* obj_bf = (__hip_bfloat16*)(ws + 20971520); // 4.2M bf16
    __hip_bfloat16* ctx_bf = obj_bf;                           // reuse after fused GEMM
    float* allout = ws + 23068672;                             // 1024 x 10240 f32
    float* h_f32  = allout;                                    // reuse after ctx
    __hip_bfloat16* h_bf = (__hip_bfloat16*)(allout + 1048576);
    float* atten  = ws + 33554432;                             // 8192
    float* Anorm  = ws + 33562624;                             // 65536
    float* cbias  = ws + 33628160;                             // 10240

    const dim3 blk(256);

    // 1. cast obj + Ws + Wo + Wc -> bf16 (one dispatch; 2048 elems/block)
    Cast4 c1;
    c1.src0 = obj;  c1.dst0 = obj_bf;
    c1.src1 = Ws_w; c1.dst1 = wbuf;
    c1.src2 = Wo_w; c1.dst2 = wbuf + 16777216;
    c1.src3 = Wc_w; c1.dst3 = wbuf + 33554432;
    c1.s1 = 2048; c1.s2 = 10240; c1.s3 = 18432;
    cast_multi<<<dim3(22528), blk, 0, stream>>>(c1);

    concat_bias<<<dim3(40), blk, 0, stream>>>(Ws_b, Wo_b, Wc_b, cbias);

    // 2. fused ws|wo|conv GEMM: [1024 x 4096] @ [10240 x 4096]^T -> allout
    gemm_dp<128><<<dim3(1280), blk, 0, stream>>>(
        (const ushort*)obj_bf, (const ushort*)wbuf, cbias, nullptr,
        allout, NTOT, D_, LDO, 3, 8192);

    // 3. cast Wt1 + Wt2 (into region freed by fused GEMM)
    Cast4 c2;
    c2.src0 = Wt1_w; c2.dst0 = wbuf_t1;
    c2.src1 = Wt2_w; c2.dst1 = wbuf_t2;
    c2.src2 = Wt1_w; c2.dst2 = wbuf_t1;   // unreachable
    c2.src3 = Wt1_w; c2.dst3 = wbuf_t1;   // unreachable
    c2.s1 = 2048; c2.s2 = 1 << 30; c2.s3 = 1 << 30;
    cast_multi<<<dim3(4096), blk, 0, stream>>>(c2);

    // 4. small/fused tail
    atten_kernel<<<dim3(RTOT), blk, 0, stream>>>(allout, phr, rel, Ww_w, Ww_b, atten);
    build_A<<<dim3(NIMG), blk, 0, stream>>>(rel, atten, Anorm);
    ctx_kernel<<<dim3(1024), blk, 0, stream>>>(Anorm, allout, ctx_bf);

    gemm_dp<64><<<dim3(256), blk, 0, stream>>>(
        (const ushort*)ctx_bf, (const ushort*)wbuf_t1, Wt1_b, nullptr,
        h_f32, NTOT, D_, DT, 0, 0);
    ln_relu_kernel<<<dim3(NTOT), blk, 0, stream>>>(h_f32, ln_g, ln_b, h_bf);
    gemm_dp<128><<<dim3(512), blk, 0, stream>>>(
        (const ushort*)h_bf, (const ushort*)wbuf_t2, Wt2_b, obj,
        out, NTOT, DT, D_, 2, 0);
}

// Round 4
// 326.746 us; speedup vs baseline: 5.2346x; 1.0403x over previous
//
#include <hip/hip_runtime.h>
#include <hip/hip_bf16.h>
#include <math.h>

#define D_   4096
#define NIMG 16
#define NPER 64
#define RPER 512
#define NTOT 1024
#define RTOT 8192
#define DC   2048
#define DT   1024
#define LDO  10240   // fused output row stride (4096 ws | 4096 wo | 2048 conv)

typedef __attribute__((ext_vector_type(4))) float f32x4;
typedef __attribute__((ext_vector_type(8))) short bf16x8;

#define GLD16(gp, lp) __builtin_amdgcn_global_load_lds( \
    (const __attribute__((address_space(1))) unsigned int*)(gp), \
    (__attribute__((address_space(3))) unsigned int*)(lp), 16, 0, 0)

// ---------------------------------------------------------------------------
// multi-region f32 -> bf16 cast. Each block converts 2048 elems.
// ---------------------------------------------------------------------------
struct Cast4 {
    const float* src0; const float* src1; const float* src2; const float* src3;
    __hip_bfloat16* dst0; __hip_bfloat16* dst1; __hip_bfloat16* dst2; __hip_bfloat16* dst3;
    int s1, s2, s3;
};

__global__ __launch_bounds__(256) void cast_multi(Cast4 a)
{
    const int b = blockIdx.x;
    const float* s; __hip_bfloat16* d; int rb;
    if (b < a.s1)      { s = a.src0; d = a.dst0; rb = b; }
    else if (b < a.s2) { s = a.src1; d = a.dst1; rb = b - a.s1; }
    else if (b < a.s3) { s = a.src2; d = a.dst2; rb = b - a.s2; }
    else               { s = a.src3; d = a.dst3; rb = b - a.s3; }
    const int i = (rb * 256 + threadIdx.x) * 8;
    float4 v0 = *(const float4*)(s + i);
    float4 v1 = *(const float4*)(s + i + 4);
    union { __hip_bfloat16 h[8]; ushort4 u[2]; } cv;
    cv.h[0] = __float2bfloat16(v0.x); cv.h[1] = __float2bfloat16(v0.y);
    cv.h[2] = __float2bfloat16(v0.z); cv.h[3] = __float2bfloat16(v0.w);
    cv.h[4] = __float2bfloat16(v1.x); cv.h[5] = __float2bfloat16(v1.y);
    cv.h[6] = __float2bfloat16(v1.z); cv.h[7] = __float2bfloat16(v1.w);
    *(ushort4*)(d + i)     = cv.u[0];
    *(ushort4*)(d + i + 4) = cv.u[1];
}

// ---------------------------------------------------------------------------
__global__ __launch_bounds__(256) void concat_bias(
    const float* __restrict__ b0, const float* __restrict__ b1,
    const float* __restrict__ b2, float* __restrict__ cb)
{
    const int i = blockIdx.x * 256 + threadIdx.x;
    float v;
    if (i < 4096) v = b0[i];
    else if (i < 8192) v = b1[i - 4096];
    else v = b2[i - 8192];
    cb[i] = v;
}

// ---------------------------------------------------------------------------
// MFMA GEMM, C = A @ B^T (+bias, act). bf16 in, f32 out.
// BM x BN tile, 256 thr (2x2 waves, wave tile BM/2 x BN/2), BK=32.
// 3 LDS buffers, 2-deep prefetch: iter t issues stage(t+2), computes buf[t],
// then waits vmcnt(NPW) (stage(t+1) landed; t+2 still in flight) + s_barrier.
// WAR safe: buf[(t+2)%3]'s readers ran in iter t-1 before barrier(t-1), and
// stage(t+2) is issued after that barrier.
// LDS row = 32 bf16 = 4 x 16B slots; slot s of row r holds K-quarter s^(r&3)
// (swizzle via pre-swizzled global source; gld_lds dest stays linear).
// mode: 0 = +bias; 2 = relu(resid + . + bias); 3 = +bias, relu iff col>=reluStart
// ---------------------------------------------------------------------------
template<int BM, int BN>
__global__ __launch_bounds__(256) void gemm_p2(
    const ushort* __restrict__ A, const ushort* __restrict__ B,
    const float* __restrict__ bias, const float* __restrict__ resid,
    float* __restrict__ C, int M, int K, int ldc, int mode, int reluStart)
{
    constexpr int MREP = BM / 32;
    constexpr int NREP = BN / 32;
    constexpr int SLOTS = (BM + BN) * 4;      // 16B slots per tile-pair
    constexpr int NPW = SLOTS / 256;          // gld_lds per thread per stage
    constexpr int BUFE = SLOTS * 8;           // ushorts per buffer

    __shared__ ushort lds[3][BUFE];

    const int t = threadIdx.x;
    const int lane = t & 63;
    const int wid = t >> 6;
    const int wr = wid >> 1, wc = wid & 1;

    const int MT = M / BM;
    const int G = gridDim.x;
    const int bid = blockIdx.x;
    const int wgid = (bid & 7) * (G >> 3) + (bid >> 3);   // XCD swizzle (G%8==0)
    const int nt = wgid / MT, mt = wgid % MT;
    const int bm = mt * BM, bn = nt * BN;

    // --- staging: thread t serves 16B slots {wid*64+lane + i*256} ---
    const ushort* gp[NPW];
    int loff[NPW];
#pragma unroll
    for (int i = 0; i < NPW; ++i) {
        const int slot = i * 256 + t;
        const bool isA = slot < BM * 4;
        const int s2 = isA ? slot : slot - BM * 4;
        const int row = s2 >> 2;
        const int q = (s2 & 3) ^ (row & 3);               // pre-swizzled source
        gp[i] = (isA ? A + (size_t)(bm + row) * K : B + (size_t)(bn + row) * K) + q * 8;
        loff[i] = slot * 8;                               // linear LDS dest
    }

    auto stage = [&](int b, int kpos) {
#pragma unroll
        for (int i = 0; i < NPW; ++i) GLD16(gp[i] + kpos, &lds[b][loff[i]]);
    };

    // --- fragment read offsets (swizzled; row&3 == lane&3) ---
    int aoff[MREP], boff[NREP];
    const int sx = (((lane >> 4) ^ (lane & 3))) << 3;
#pragma unroll
    for (int m = 0; m < MREP; ++m)
        aoff[m] = (wr * (BM / 2) + (lane & 15) + m * 16) * 32 + sx;
#pragma unroll
    for (int n = 0; n < NREP; ++n)
        boff[n] = BM * 32 + (wc * (BN / 2) + (lane & 15) + n * 16) * 32 + sx;

    f32x4 acc[MREP][NREP] = {};

    const int NT = K >> 5;   // NT >= 2 required (K >= 64)
    stage(0, 0);
    stage(1, 32);
    if constexpr (NPW == 2) asm volatile("s_waitcnt vmcnt(2)" ::: "memory");
    else if constexpr (NPW == 3) asm volatile("s_waitcnt vmcnt(3)" ::: "memory");
    else asm volatile("s_waitcnt vmcnt(4)" ::: "memory");
    __builtin_amdgcn_sched_barrier(0);
    __builtin_amdgcn_s_barrier();
    __builtin_amdgcn_sched_barrier(0);

    for (int tt = 0; tt < NT; ++tt) {
        const bool pf = (tt + 2 < NT);
        if (pf) stage((tt + 2) % 3, (tt + 2) << 5);
        __builtin_amdgcn_sched_barrier(0);

        const ushort* lb = lds[tt % 3];
        bf16x8 af[MREP], bfv[NREP];
#pragma unroll
        for (int m = 0; m < MREP; ++m) af[m] = *(const bf16x8*)(lb + aoff[m]);
#pragma unroll
        for (int n = 0; n < NREP; ++n) bfv[n] = *(const bf16x8*)(lb + boff[n]);
#pragma unroll
        for (int m = 0; m < MREP; ++m)
#pragma unroll
            for (int n = 0; n < NREP; ++n)
                acc[m][n] = __builtin_amdgcn_mfma_f32_16x16x32_bf16(
                    af[m], bfv[n], acc[m][n], 0, 0, 0);

        __builtin_amdgcn_sched_barrier(0);
        if (pf) {
            if constexpr (NPW == 2) asm volatile("s_waitcnt vmcnt(2)" ::: "memory");
            else if constexpr (NPW == 3) asm volatile("s_waitcnt vmcnt(3)" ::: "memory");
            else asm volatile("s_waitcnt vmcnt(4)" ::: "memory");
        } else {
            asm volatile("s_waitcnt vmcnt(0)" ::: "memory");
        }
        __builtin_amdgcn_sched_barrier(0);
        __builtin_amdgcn_s_barrier();
        __builtin_amdgcn_sched_barrier(0);
    }

    // --- epilogue: C/D map col=lane&15, row=(lane>>4)*4+reg ---
    const int col0 = bn + wc * (BN / 2) + (lane & 15);
    const int row0 = bm + wr * (BM / 2) + ((lane >> 4) << 2);
#pragma unroll
    for (int m = 0; m < MREP; ++m) {
#pragma unroll
        for (int n = 0; n < NREP; ++n) {
            const int cn = col0 + n * 16;
            const float bz = bias[cn];
#pragma unroll
            for (int rg = 0; rg < 4; ++rg) {
                const int gm = row0 + m * 16 + rg;
                float v = acc[m][n][rg] + bz;
                if (mode == 2) v = fmaxf(v + resid[(size_t)gm * ldc + cn], 0.f);
                else if (mode == 3 && cn >= reluStart) v = fmaxf(v, 0.f);
                C[(size_t)gm * ldc + cn] = v;
            }
        }
    }
}

// ---------------------------------------------------------------------------
// atten[r] = sum_d ws[s[r],d] * wo[o[r],d] * phr[r,d] * Www[d]  + Wwb
// ---------------------------------------------------------------------------
__global__ __launch_bounds__(256) void atten_kernel(
    const float* __restrict__ allout, const float* __restrict__ phr,
    const int* __restrict__ rel, const float* __restrict__ Www,
    const float* __restrict__ Wwb, float* __restrict__ atten)
{
    const int r = blockIdx.x;
    const int s = rel[r * 3 + 1], o = rel[r * 3 + 2];
    const int t = threadIdx.x;
    const float4* pws = (const float4*)(allout + (size_t)s * LDO);
    const float4* pwo = (const float4*)(allout + (size_t)o * LDO + 4096);
    const float4* pph = (const float4*)(phr + (size_t)r * D_);
    const float4* pww = (const float4*)Www;
    float sum = 0.f;
    for (int qq = t; qq < D_ / 4; qq += 256) {
        float4 a = pws[qq], b = pwo[qq], c = pph[qq], w = pww[qq];
        sum += a.x * b.x * c.x * w.x + a.y * b.y * c.y * w.y
             + a.z * b.z * c.z * w.z + a.w * b.w * c.w * w.w;
    }
    for (int off = 32; off > 0; off >>= 1) sum += __shfl_down(sum, off);
    __shared__ float red[4];
    if ((t & 63) == 0) red[t >> 6] = sum;
    __syncthreads();
    if (t == 0) atten[r] = red[0] + red[1] + red[2] + red[3] + Wwb[0];
}

// ---------------------------------------------------------------------------
__global__ __launch_bounds__(256) void build_A(
    const int* __restrict__ rel, const float* __restrict__ atten,
    float* __restrict__ Anorm)
{
    const int g = blockIdx.x;
    const int t = threadIdx.x;
    __shared__ float Am[64][64];
    __shared__ float S[64];
    __shared__ int headSh;
    for (int i = t; i < 4096; i += 256) ((float*)Am)[i] = 0.f;
    if (t == 0) headSh = 0x7fffffff;

    int lmin = 0x7fffffff;
    for (int rr = t; rr < RPER; rr += 256) {
        const int base = (g * RPER + rr) * 3;
        lmin = min(lmin, min(rel[base + 1], rel[base + 2]));
    }
    for (int off = 32; off > 0; off >>= 1) lmin = min(lmin, __shfl_down(lmin, off));
    __syncthreads();
    if ((t & 63) == 0) atomicMin(&headSh, lmin);
    __syncthreads();
    const int head = headSh;

    for (int rr = t; rr < RPER; rr += 256) {
        const int base = (g * RPER + rr) * 3;
        atomicAdd(&Am[rel[base + 1] - head][rel[base + 2] - head],
                  atten[g * RPER + rr]);
    }
    __syncthreads();

    for (int idx = t; idx < 4096; idx += 256) {
        const int i = idx >> 6, j = idx & 63;
        float v = 1.f / (1.f + expf(-Am[i][j]));
        if (i == j) v = 0.f;
        Am[i][j] = v;
    }
    __syncthreads();

    if (t < 64) {
        float sum = 0.f;
        for (int k = 0; k < 64; ++k) sum += Am[t][k];
        S[t] = sum;
    }
    __syncthreads();

    float* outg = Anorm + (size_t)g * 4096;
    for (int idx = t; idx < 4096; idx += 256) {
        const int j = idx & 63;
        outg[idx] = ((const float*)Am)[idx] / S[j];
    }
}

// ---------------------------------------------------------------------------
__device__ __forceinline__ void fma4(float4& d, float s, const float4 c) {
    d.x = fmaf(s, c.x, d.x); d.y = fmaf(s, c.y, d.y);
    d.z = fmaf(s, c.z, d.z); d.w = fmaf(s, c.w, d.w);
}
__device__ __forceinline__ void st4bf(__hip_bfloat16* p, float4 v) {
    union { __hip_bfloat16 h[4]; ushort4 u; } cv;
    cv.h[0] = __float2bfloat16(v.x); cv.h[1] = __float2bfloat16(v.y);
    cv.h[2] = __float2bfloat16(v.z); cv.h[3] = __float2bfloat16(v.w);
    *(ushort4*)p = cv.u;
}

__global__ __launch_bounds__(256) void ctx_kernel(
    const float* __restrict__ Anorm, const float* __restrict__ allout,
    __hip_bfloat16* __restrict__ ctx)
{
    const int g = blockIdx.x >> 6;
    const int i = blockIdx.x & 63;
    const int t = threadIdx.x;
    __shared__ float Arow[64], Acol[64];
    if (t < 64) Arow[t] = Anorm[(size_t)g * 4096 + i * 64 + t];
    else if (t < 128) { const int j = t - 64; Acol[j] = Anorm[(size_t)g * 4096 + j * 64 + i]; }
    __syncthreads();

    const float* cg = allout + (size_t)g * NPER * LDO + 8192;
    float4 a0 = {0,0,0,0}, a1 = a0, a2 = a0, a3 = a0;
    for (int j = 0; j < 64; ++j) {
        const float ar = Arow[j], ac = Acol[j];
        float4 c0 = *(const float4*)(cg + (size_t)j * LDO + (t << 2));
        float4 c1 = *(const float4*)(cg + (size_t)j * LDO + 1024 + (t << 2));
        fma4(a0, ar, c0); fma4(a1, ar, c1);
        fma4(a2, ac, c0); fma4(a3, ac, c1);
    }
    __hip_bfloat16* crow = ctx + (size_t)(g * NPER + i) * D_;
    st4bf(crow + (t << 2),        a0);
    st4bf(crow + 1024 + (t << 2), a1);
    st4bf(crow + 2048 + (t << 2), a2);
    st4bf(crow + 3072 + (t << 2), a3);
}

// ---------------------------------------------------------------------------
__global__ __launch_bounds__(256) void ln_relu_kernel(
    const float* __restrict__ h, const float* __restrict__ gamma,
    const float* __restrict__ beta, __hip_bfloat16* __restrict__ hb)
{
    const int row = blockIdx.x;
    const int t = threadIdx.x;
    const float* hr = h + (size_t)row * DT;
    float4 v = *(const float4*)(hr + (t << 2));
    float s  = v.x + v.y + v.z + v.w;
    float ss = v.x * v.x + v.y * v.y + v.z * v.z + v.w * v.w;
    for (int off = 32; off > 0; off >>= 1) {
        s  += __shfl_down(s, off);
        ss += __shfl_down(ss, off);
    }
    __shared__ float rs[4], rss[4];
    if ((t & 63) == 0) { rs[t >> 6] = s; rss[t >> 6] = ss; }
    __syncthreads();
    const float tot  = rs[0] + rs[1] + rs[2] + rs[3];
    const float tot2 = rss[0] + rss[1] + rss[2] + rss[3];
    const float mu   = tot * (1.f / DT);
    const float var  = tot2 * (1.f / DT) - mu * mu;
    const float rstd = rsqrtf(var + 1e-5f);
    float4 g4 = *(const float4*)(gamma + (t << 2));
    float4 b4 = *(const float4*)(beta + (t << 2));
    float4 o;
    o.x = fmaxf(fmaf((v.x - mu) * rstd, g4.x, b4.x), 0.f);
    o.y = fmaxf(fmaf((v.y - mu) * rstd, g4.y, b4.y), 0.f);
    o.z = fmaxf(fmaf((v.z - mu) * rstd, g4.z, b4.z), 0.f);
    o.w = fmaxf(fmaf((v.w - mu) * rstd, g4.w, b4.w), 0.f);
    st4bf(hb + (size_t)row * DT + (t << 2), o);
}

// ---------------------------------------------------------------------------
extern "C" void kernel_launch(void* const* d_in, const int* in_sizes, int n_in,
                              void* d_out, int out_size, void* d_ws, size_t ws_size,
                              hipStream_t stream)
{
    const float* obj   = (const float*)d_in[0];
    const float* phr   = (const float*)d_in[1];
    const int*   rel   = (const int*)d_in[3];
    const float* Ws_w  = (const float*)d_in[5];
    const float* Ws_b  = (const float*)d_in[6];
    const float* Wo_w  = (const float*)d_in[7];
    const float* Wo_b  = (const float*)d_in[8];
    const float* Ww_w  = (const float*)d_in[9];
    const float* Ww_b  = (const float*)d_in[10];
    const float* Wc_w  = (const float*)d_in[11];
    const float* Wc_b  = (const float*)d_in[12];
    const float* Wt1_w = (const float*)d_in[13];
    const float* Wt1_b = (const float*)d_in[14];
    const float* ln_g  = (const float*)d_in[15];
    const float* ln_b  = (const float*)d_in[16];
    const float* Wt2_w = (const float*)d_in[17];
    const float* Wt2_b = (const float*)d_in[18];
    float* out = (float*)d_out;

    float* ws = (float*)d_ws;
    // workspace layout (float units), peak ~134.6 MB:
    __hip_bfloat16* wbuf   = (__hip_bfloat16*)ws;              // Ws|Wo|Wc concat, 41.9M bf16
    __hip_bfloat16* wbuf_t1 = wbuf;                            // reuse after fused GEMM
    __hip_bfloat16* wbuf_t2 = wbuf + 4194304;
    __hip_bfloat16* obj_bf = (__hip_bfloat16*)(ws + 20971520); // 4.2M bf16
    __hip_bfloat16* ctx_bf = obj_bf;                           // reuse after fused GEMM
    float* allout = ws + 23068672;                             // 1024 x 10240 f32
    float* h_f32  = allout;                                    // reuse after ctx
    __hip_bfloat16* h_bf = (__hip_bfloat16*)(allout + 1048576);
    float* atten  = ws + 33554432;                             // 8192
    float* Anorm  = ws + 33562624;                             // 65536
    float* cbias  = ws + 33628160;                             // 10240

    const dim3 blk(256);

    // 1. cast obj + Ws + Wo + Wc -> bf16 (one dispatch; 2048 elems/block)
    Cast4 c1;
    c1.src0 = obj;  c1.dst0 = obj_bf;
    c1.src1 = Ws_w; c1.dst1 = wbuf;
    c1.src2 = Wo_w; c1.dst2 = wbuf + 16777216;
    c1.src3 = Wc_w; c1.dst3 = wbuf + 33554432;
    c1.s1 = 2048; c1.s2 = 10240; c1.s3 = 18432;
    cast_multi<<<dim3(22528), blk, 0, stream>>>(c1);

    concat_bias<<<dim3(40), blk, 0, stream>>>(Ws_b, Wo_b, Wc_b, cbias);

    // 2. fused ws|wo|conv GEMM: [1024 x 4096] @ [10240 x 4096]^T -> allout
    gemm_p2<128, 128><<<dim3(640), blk, 0, stream>>>(
        (const ushort*)obj_bf, (const ushort*)wbuf, cbias, nullptr,
        allout, NTOT, D_, LDO, 3, 8192);

    // 3. cast Wt1 + Wt2 (into region freed by fused GEMM)
    Cast4 c2;
    c2.src0 = Wt1_w; c2.dst0 = wbuf_t1;
    c2.src1 = Wt2_w; c2.dst1 = wbuf_t2;
    c2.src2 = Wt1_w; c2.dst2 = wbuf_t1;   // unreachable
    c2.src3 = Wt1_w; c2.dst3 = wbuf_t1;   // unreachable
    c2.s1 = 2048; c2.s2 = 1 << 30; c2.s3 = 1 << 30;
    cast_multi<<<dim3(4096), blk, 0, stream>>>(c2);

    // 4. small/fused tail
    atten_kernel<<<dim3(RTOT), blk, 0, stream>>>(allout, phr, rel, Ww_w, Ww_b, atten);
    build_A<<<dim3(NIMG), blk, 0, stream>>>(rel, atten, Anorm);
    ctx_kernel<<<dim3(1024), blk, 0, stream>>>(Anorm, allout, ctx_bf);

    gemm_p2<64, 64><<<dim3(256), blk, 0, stream>>>(
        (const ushort*)ctx_bf, (const ushort*)wbuf_t1, Wt1_b, nullptr,
        h_f32, NTOT, D_, DT, 0, 0);
    ln_relu_kernel<<<dim3(NTOT), blk, 0, stream>>>(h_f32, ln_g, ln_b, h_bf);
    gemm_p2<128, 128><<<dim3(256), blk, 0, stream>>>(
        (const ushort*)h_bf, (const ushort*)wbuf_t2, Wt2_b, obj,
        out, NTOT, DT, D_, 2, 0);
}